// Round 1
// baseline (4641.256 us; speedup 1.0000x reference)
//
#include <hip/hip_runtime.h>
#include <math.h>

#define N_NODES 50000
#define N_EDGES 400000
#define NFEAT 512
#define NHID 256
#define NCLASS 8

// ---------------- degree / norm prep ----------------

__global__ void init_deg_k(float* deg, float* deg3) {
    int i = blockIdx.x * blockDim.x + threadIdx.x;
    if (i < N_NODES) { deg[i] = 1.0f; deg3[i] = 1.0f; }
}

__global__ void edge_deg_k(const float* __restrict__ p, const int* __restrict__ dst,
                           float* __restrict__ deg, float* __restrict__ deg3,
                           float* __restrict__ ew_out) {
    int e = blockIdx.x * blockDim.x + threadIdx.x;
    if (e >= N_EDGES) return;
    float ew = 1.0f / (1.0f + expf(-p[e]));
    ew_out[e] = ew;
    int d = dst[e];
    atomicAdd(&deg[d], ew);
    atomicAdd(&deg3[d], 1.0f);
}

__global__ void finalize_dinv_k(float* deg, float* deg3) {
    int i = blockIdx.x * blockDim.x + threadIdx.x;
    if (i < N_NODES) {
        deg[i]  = 1.0f / sqrtf(deg[i]);
        deg3[i] = 1.0f / sqrtf(deg3[i]);
    }
}

__global__ void compute_norm_k(const int* __restrict__ src, const int* __restrict__ dst,
                               const float* __restrict__ dinv, const float* __restrict__ dinv3,
                               float* __restrict__ norm /* in: ew */, float* __restrict__ norm3) {
    int e = blockIdx.x * blockDim.x + threadIdx.x;
    if (e >= N_EDGES) return;
    int s = src[e], d = dst[e];
    float ew = norm[e];
    norm[e]  = dinv[s] * ew * dinv[d];
    norm3[e] = dinv3[s] * dinv3[d];
}

// ---------------- f32 GEMM: C[M x 256] = A[M x K] @ W[K x 256] ----------------
// 64x64 tile, 256 threads, 4x4 per thread, BK=16.

__global__ __launch_bounds__(256) void gemm_f32_k(const float* __restrict__ A,
                                                  const float* __restrict__ W,
                                                  float* __restrict__ C, int M, int K) {
    __shared__ float As[16][65];   // padded: conflict-free column writes
    __shared__ float Bs[16][64];
    int tid = threadIdx.x;
    int bm = blockIdx.x, bn = blockIdx.y;
    int tm = (tid >> 4) << 2;      // 0..60
    int tn = (tid & 15) << 2;      // 0..60
    int row0 = bm * 64;
    float acc[4][4] = {};

    for (int k0 = 0; k0 < K; k0 += 16) {
        {   // A tile: 64 rows x 16 k, one float4 per thread along k
            int r  = tid >> 2;
            int kk = (tid & 3) << 2;
            int gr = row0 + r;
            float4 v = make_float4(0.f, 0.f, 0.f, 0.f);
            if (gr < M) v = *(const float4*)&A[(size_t)gr * K + k0 + kk];
            As[kk + 0][r] = v.x; As[kk + 1][r] = v.y;
            As[kk + 2][r] = v.z; As[kk + 3][r] = v.w;
        }
        {   // B tile: 16 k x 64 n
            int k = tid >> 4;
            int n = (tid & 15) << 2;
            *(float4*)&Bs[k][n] = *(const float4*)&W[(size_t)(k0 + k) * 256 + bn * 64 + n];
        }
        __syncthreads();
        #pragma unroll
        for (int k = 0; k < 16; ++k) {
            float a0 = As[k][tm + 0], a1 = As[k][tm + 1], a2 = As[k][tm + 2], a3 = As[k][tm + 3];
            float b0 = Bs[k][tn + 0], b1 = Bs[k][tn + 1], b2 = Bs[k][tn + 2], b3 = Bs[k][tn + 3];
            acc[0][0] += a0 * b0; acc[0][1] += a0 * b1; acc[0][2] += a0 * b2; acc[0][3] += a0 * b3;
            acc[1][0] += a1 * b0; acc[1][1] += a1 * b1; acc[1][2] += a1 * b2; acc[1][3] += a1 * b3;
            acc[2][0] += a2 * b0; acc[2][1] += a2 * b1; acc[2][2] += a2 * b2; acc[2][3] += a2 * b3;
            acc[3][0] += a3 * b0; acc[3][1] += a3 * b1; acc[3][2] += a3 * b2; acc[3][3] += a3 * b3;
        }
        __syncthreads();
    }
    #pragma unroll
    for (int i = 0; i < 4; ++i) {
        int gr = row0 + tm + i;
        if (gr < M) {
            float4 v = make_float4(acc[i][0], acc[i][1], acc[i][2], acc[i][3]);
            *(float4*)&C[(size_t)gr * 256 + bn * 64 + tn] = v;
        }
    }
}

// ---------------- aggregation ----------------

// agg[i, :] = h[i, :] * dinv[i]^2   (self-loop term, also initializes agg)
__global__ void self_init_k(const float* __restrict__ h, const float* __restrict__ dinv,
                            float* __restrict__ agg) {
    int idx = blockIdx.x * blockDim.x + threadIdx.x;   // over N*64 float4s
    if (idx >= N_NODES * 64) return;
    int node = idx >> 6;
    float di = dinv[node];
    float s = di * di;
    float4 v = *(const float4*)&h[(size_t)idx * 4];
    v.x *= s; v.y *= s; v.z *= s; v.w *= s;
    *(float4*)&agg[(size_t)idx * 4] = v;
}

// agg[dst] += h[src] * norm   over all edges, 64 float4-lanes per edge
__global__ void scatter_k(const float* __restrict__ h, const int* __restrict__ src,
                          const int* __restrict__ dst, const float* __restrict__ norm,
                          float* __restrict__ agg) {
    int idx = blockIdx.x * blockDim.x + threadIdx.x;
    int e = idx >> 6;
    if (e >= N_EDGES) return;
    int f4 = idx & 63;
    int s = src[e], d = dst[e];
    float nw = norm[e];
    float4 v = *(const float4*)&h[(size_t)s * 256 + f4 * 4];
    float* out = &agg[(size_t)d * 256 + f4 * 4];
    atomicAdd(out + 0, v.x * nw);
    atomicAdd(out + 1, v.y * nw);
    atomicAdd(out + 2, v.z * nw);
    atomicAdd(out + 3, v.w * nw);
}

template <bool RELU>
__global__ void bias_act_k(float* __restrict__ x, const float* __restrict__ b) {
    int idx = blockIdx.x * blockDim.x + threadIdx.x;   // over N*64 float4s
    if (idx >= N_NODES * 64) return;
    int f4 = idx & 63;
    float4 bv = *(const float4*)&b[f4 * 4];
    float4 v = *(const float4*)&x[(size_t)idx * 4];
    v.x += bv.x; v.y += bv.y; v.z += bv.z; v.w += bv.w;
    if (RELU) {
        v.x = fmaxf(v.x, 0.f); v.y = fmaxf(v.y, 0.f);
        v.z = fmaxf(v.z, 0.f); v.w = fmaxf(v.w, 0.f);
    }
    *(float4*)&x[(size_t)idx * 4] = v;
}

// ---------------- final linear (accumulated per 256-col segment) + log_softmax ----------------

template <bool FIRST>
__global__ __launch_bounds__(256) void logits_acc_k(const float* __restrict__ x,
                                                    const float* __restrict__ Wlin,
                                                    const float* __restrict__ blin,
                                                    float* __restrict__ logits, int seg) {
    __shared__ float Ws[256 * 8];
    int tid = threadIdx.x;
    const float* Wseg = Wlin + (size_t)seg * 256 * 8;
    for (int i = tid; i < 2048; i += 256) Ws[i] = Wseg[i];
    __syncthreads();
    int row = blockIdx.x * 32 + (tid >> 3);
    int c = tid & 7;
    if (row >= N_NODES) return;
    const float* xr = x + (size_t)row * 256;
    float acc = 0.f;
    #pragma unroll 8
    for (int k = 0; k < 256; ++k) acc += xr[k] * Ws[k * 8 + c];
    float* lp = &logits[(size_t)row * 8 + c];
    if (FIRST) *lp = acc + blin[c];
    else       *lp += acc;
}

__global__ void log_softmax_k(const float* __restrict__ logits, float* __restrict__ out) {
    int row = blockIdx.x * blockDim.x + threadIdx.x;
    if (row >= N_NODES) return;
    float4 a = *(const float4*)&logits[(size_t)row * 8];
    float4 b = *(const float4*)&logits[(size_t)row * 8 + 4];
    float m = fmaxf(fmaxf(fmaxf(a.x, a.y), fmaxf(a.z, a.w)),
                    fmaxf(fmaxf(b.x, b.y), fmaxf(b.z, b.w)));
    float s = expf(a.x - m) + expf(a.y - m) + expf(a.z - m) + expf(a.w - m)
            + expf(b.x - m) + expf(b.y - m) + expf(b.z - m) + expf(b.w - m);
    float ls = logf(s) + m;
    float* o = &out[(size_t)row * 8];
    o[0] = a.x - ls; o[1] = a.y - ls; o[2] = a.z - ls; o[3] = a.w - ls;
    o[4] = b.x - ls; o[5] = b.y - ls; o[6] = b.z - ls; o[7] = b.w - ls;
}

// ---------------- driver ----------------

extern "C" void kernel_launch(void* const* d_in, const int* in_sizes, int n_in,
                              void* d_out, int out_size, void* d_ws, size_t ws_size,
                              hipStream_t stream) {
    const float* x    = (const float*)d_in[0];
    const int*   ei   = (const int*)d_in[1];
    const float* ewp  = (const float*)d_in[2];
    const float* W1   = (const float*)d_in[3];
    const float* b1   = (const float*)d_in[4];
    const float* W2   = (const float*)d_in[5];
    const float* b2   = (const float*)d_in[6];
    const float* W3   = (const float*)d_in[7];
    const float* b3   = (const float*)d_in[8];
    const float* Wlin = (const float*)d_in[9];
    const float* blin = (const float*)d_in[10];
    float* out = (float*)d_out;

    const int* src = ei;
    const int* dst = ei + N_EDGES;

    float* ws = (float*)d_ws;
    float* norm   = ws;                          // E
    float* norm3  = norm  + N_EDGES;             // E
    float* dinv   = norm3 + N_EDGES;             // N (deg -> dinv in place)
    float* dinv3  = dinv  + N_NODES;             // N
    float* logits = dinv3 + N_NODES;             // N*8
    float* bufA   = logits + (size_t)N_NODES * 8;            // N*256 (h)
    float* bufB   = bufA + (size_t)N_NODES * 256;            // N*256
    float* bufC   = bufB + (size_t)N_NODES * 256;            // N*256

    dim3 blk(256);
    int nodeBlocks  = (N_NODES + 255) / 256;
    int edgeBlocks  = (N_EDGES + 255) / 256;
    int featBlocks  = (N_NODES * 64 + 255) / 256;      // N*256 elems as float4
    int scatBlocks  = (N_EDGES * 64 + 255) / 256;
    int rowBlocks32 = (N_NODES + 31) / 32;

    // prep
    init_deg_k<<<nodeBlocks, blk, 0, stream>>>(dinv, dinv3);
    edge_deg_k<<<edgeBlocks, blk, 0, stream>>>(ewp, dst, dinv, dinv3, norm);
    finalize_dinv_k<<<nodeBlocks, blk, 0, stream>>>(dinv, dinv3);
    compute_norm_k<<<edgeBlocks, blk, 0, stream>>>(src, dst, dinv, dinv3, norm, norm3);

    dim3 gemmGrid((N_NODES + 63) / 64, 4);

    // ---- layer 1: x -> bufB (x1), h in bufA
    gemm_f32_k<<<gemmGrid, blk, 0, stream>>>(x, W1, bufA, N_NODES, NFEAT);
    self_init_k<<<featBlocks, blk, 0, stream>>>(bufA, dinv, bufB);
    scatter_k<<<scatBlocks, blk, 0, stream>>>(bufA, src, dst, norm, bufB);
    bias_act_k<true><<<featBlocks, blk, 0, stream>>>(bufB, b1);
    logits_acc_k<true><<<rowBlocks32, blk, 0, stream>>>(bufB, Wlin, blin, logits, 0);

    // ---- layer 2: bufB (x1) -> bufC (x2), h in bufA
    gemm_f32_k<<<gemmGrid, blk, 0, stream>>>(bufB, W2, bufA, N_NODES, NHID);
    self_init_k<<<featBlocks, blk, 0, stream>>>(bufA, dinv, bufC);
    scatter_k<<<scatBlocks, blk, 0, stream>>>(bufA, src, dst, norm, bufC);
    bias_act_k<true><<<featBlocks, blk, 0, stream>>>(bufC, b2);
    logits_acc_k<false><<<rowBlocks32, blk, 0, stream>>>(bufC, Wlin, blin, logits, 1);

    // ---- layer 3: bufC (x2) -> bufB (x3), h in bufA, ones edge weights
    gemm_f32_k<<<gemmGrid, blk, 0, stream>>>(bufC, W3, bufA, N_NODES, NHID);
    self_init_k<<<featBlocks, blk, 0, stream>>>(bufA, dinv3, bufB);
    scatter_k<<<scatBlocks, blk, 0, stream>>>(bufA, src, dst, norm3, bufB);
    bias_act_k<false><<<featBlocks, blk, 0, stream>>>(bufB, b3);
    logits_acc_k<false><<<rowBlocks32, blk, 0, stream>>>(bufB, Wlin, blin, logits, 2);

    // ---- output
    log_softmax_k<<<nodeBlocks, blk, 0, stream>>>(logits, out);
}

// Round 2
// 921.744 us; speedup vs baseline: 5.0353x; 5.0353x over previous
//
#include <hip/hip_runtime.h>
#include <math.h>

#define N_NODES 50000
#define N_EDGES 400000
#define NFEAT 512
#define NHID 256
#define NCLASS 8

// ---------------- prep: degrees, norms, CSR ----------------

__global__ void init_k(float* deg, float* deg3, int* cnt, int* cur) {
    int i = blockIdx.x * blockDim.x + threadIdx.x;
    if (i < N_NODES) { deg[i] = 1.0f; deg3[i] = 1.0f; cnt[i] = 0; cur[i] = 0; }
}

__global__ void edge_deg_k(const float* __restrict__ p, const int* __restrict__ dst,
                           float* __restrict__ deg, float* __restrict__ deg3,
                           int* __restrict__ cnt, float* __restrict__ ew_out) {
    int e = blockIdx.x * blockDim.x + threadIdx.x;
    if (e >= N_EDGES) return;
    float ew = 1.0f / (1.0f + expf(-p[e]));
    ew_out[e] = ew;
    int d = dst[e];
    atomicAdd(&deg[d], ew);
    atomicAdd(&deg3[d], 1.0f);
    atomicAdd(&cnt[d], 1);
}

__global__ void finalize_dinv_k(float* deg, float* deg3) {
    int i = blockIdx.x * blockDim.x + threadIdx.x;
    if (i < N_NODES) {
        deg[i]  = 1.0f / sqrtf(deg[i]);
        deg3[i] = 1.0f / sqrtf(deg3[i]);
    }
}

__global__ void compute_norm_k(const int* __restrict__ src, const int* __restrict__ dst,
                               const float* __restrict__ dinv, const float* __restrict__ dinv3,
                               float* __restrict__ norm /* in: ew */, float* __restrict__ norm3) {
    int e = blockIdx.x * blockDim.x + threadIdx.x;
    if (e >= N_EDGES) return;
    int s = src[e], d = dst[e];
    float ew = norm[e];
    norm[e]  = dinv[s] * ew * dinv[d];
    norm3[e] = dinv3[s] * dinv3[d];
}

// single-block exclusive scan over cnt[N] -> row_start[N+1]
__global__ __launch_bounds__(1024) void scan_k(const int* __restrict__ cnt,
                                               int* __restrict__ row_start) {
    __shared__ int tmp[1024];
    const int CH = (N_NODES + 1023) / 1024;   // 49
    int t = threadIdx.x;
    int base = t * CH;
    int s = 0;
    for (int i = 0; i < CH; ++i) {
        int idx = base + i;
        if (idx < N_NODES) s += cnt[idx];
    }
    tmp[t] = s;
    __syncthreads();
    for (int off = 1; off < 1024; off <<= 1) {
        int v = 0;
        if (t >= off) v = tmp[t - off];
        __syncthreads();
        if (t >= off) tmp[t] += v;
        __syncthreads();
    }
    int run = (t == 0) ? 0 : tmp[t - 1];
    for (int i = 0; i < CH; ++i) {
        int idx = base + i;
        if (idx < N_NODES) { row_start[idx] = run; run += cnt[idx]; }
    }
    if (t == 1023) row_start[N_NODES] = tmp[1022];  // == total E (tail chunks empty)
}

// fill CSR slots with packed (src, norm, norm3)
__global__ void fill_k(const int* __restrict__ src, const int* __restrict__ dst,
                       const float* __restrict__ norm, const float* __restrict__ norm3,
                       const int* __restrict__ row_start, int* __restrict__ cur,
                       int* __restrict__ e_src, float* __restrict__ e_w,
                       float* __restrict__ e_w3) {
    int e = blockIdx.x * blockDim.x + threadIdx.x;
    if (e >= N_EDGES) return;
    int d = dst[e];
    int p = atomicAdd(&cur[d], 1);
    int slot = row_start[d] + p;
    e_src[slot] = src[e];
    e_w[slot]   = norm[e];
    e_w3[slot]  = norm3[e];
}

// ---------------- f32 GEMM: C[M x 256] = A[M x K] @ W[K x 256] ----------------

__global__ __launch_bounds__(256) void gemm_f32_k(const float* __restrict__ A,
                                                  const float* __restrict__ W,
                                                  float* __restrict__ C, int M, int K) {
    __shared__ float As[16][65];
    __shared__ float Bs[16][64];
    int tid = threadIdx.x;
    int bm = blockIdx.x, bn = blockIdx.y;
    int tm = (tid >> 4) << 2;
    int tn = (tid & 15) << 2;
    int row0 = bm * 64;
    float acc[4][4] = {};

    for (int k0 = 0; k0 < K; k0 += 16) {
        {
            int r  = tid >> 2;
            int kk = (tid & 3) << 2;
            int gr = row0 + r;
            float4 v = make_float4(0.f, 0.f, 0.f, 0.f);
            if (gr < M) v = *(const float4*)&A[(size_t)gr * K + k0 + kk];
            As[kk + 0][r] = v.x; As[kk + 1][r] = v.y;
            As[kk + 2][r] = v.z; As[kk + 3][r] = v.w;
        }
        {
            int k = tid >> 4;
            int n = (tid & 15) << 2;
            *(float4*)&Bs[k][n] = *(const float4*)&W[(size_t)(k0 + k) * 256 + bn * 64 + n];
        }
        __syncthreads();
        #pragma unroll
        for (int k = 0; k < 16; ++k) {
            float a0 = As[k][tm + 0], a1 = As[k][tm + 1], a2 = As[k][tm + 2], a3 = As[k][tm + 3];
            float b0 = Bs[k][tn + 0], b1 = Bs[k][tn + 1], b2 = Bs[k][tn + 2], b3 = Bs[k][tn + 3];
            acc[0][0] += a0 * b0; acc[0][1] += a0 * b1; acc[0][2] += a0 * b2; acc[0][3] += a0 * b3;
            acc[1][0] += a1 * b0; acc[1][1] += a1 * b1; acc[1][2] += a1 * b2; acc[1][3] += a1 * b3;
            acc[2][0] += a2 * b0; acc[2][1] += a2 * b1; acc[2][2] += a2 * b2; acc[2][3] += a2 * b3;
            acc[3][0] += a3 * b0; acc[3][1] += a3 * b1; acc[3][2] += a3 * b2; acc[3][3] += a3 * b3;
        }
        __syncthreads();
    }
    #pragma unroll
    for (int i = 0; i < 4; ++i) {
        int gr = row0 + tm + i;
        if (gr < M) {
            float4 v = make_float4(acc[i][0], acc[i][1], acc[i][2], acc[i][3]);
            *(float4*)&C[(size_t)gr * 256 + bn * 64 + tn] = v;
        }
    }
}

// ---------------- fused gather: agg = sum_in h[src]*w + h[node]*dinv^2 + bias, opt ReLU ----------------
// one wave (64 lanes) per node; lane owns one float4 of the 256 features.

template <bool RELU>
__global__ __launch_bounds__(256) void gather_k(const float* __restrict__ h,
                                                const int* __restrict__ row_start,
                                                const int* __restrict__ e_src,
                                                const float* __restrict__ e_w,
                                                const float* __restrict__ dinv,
                                                const float* __restrict__ bias,
                                                float* __restrict__ out) {
    int node = blockIdx.x * 4 + (threadIdx.x >> 6);
    if (node >= N_NODES) return;
    int lane = threadIdx.x & 63;
    const float4* h4 = (const float4*)h;

    float di = dinv[node];
    float sw = di * di;
    float4 v = h4[(size_t)node * 64 + lane];
    float4 acc = make_float4(v.x * sw, v.y * sw, v.z * sw, v.w * sw);

    int beg = row_start[node], end = row_start[node + 1];
    for (int j = beg; j < end; ++j) {
        int sn  = e_src[j];
        float w = e_w[j];
        float4 u = h4[(size_t)sn * 64 + lane];
        acc.x += u.x * w; acc.y += u.y * w; acc.z += u.z * w; acc.w += u.w * w;
    }
    float4 bv = ((const float4*)bias)[lane];
    acc.x += bv.x; acc.y += bv.y; acc.z += bv.z; acc.w += bv.w;
    if (RELU) {
        acc.x = fmaxf(acc.x, 0.f); acc.y = fmaxf(acc.y, 0.f);
        acc.z = fmaxf(acc.z, 0.f); acc.w = fmaxf(acc.w, 0.f);
    }
    ((float4*)out)[(size_t)node * 64 + lane] = acc;
}

// ---------------- final linear (accumulated per 256-col segment) + log_softmax ----------------

template <bool FIRST>
__global__ __launch_bounds__(256) void logits_acc_k(const float* __restrict__ x,
                                                    const float* __restrict__ Wlin,
                                                    const float* __restrict__ blin,
                                                    float* __restrict__ logits, int seg) {
    __shared__ float Ws[256 * 8];
    int tid = threadIdx.x;
    const float* Wseg = Wlin + (size_t)seg * 256 * 8;
    for (int i = tid; i < 2048; i += 256) Ws[i] = Wseg[i];
    __syncthreads();
    int row = blockIdx.x * 32 + (tid >> 3);
    int c = tid & 7;
    if (row >= N_NODES) return;
    const float* xr = x + (size_t)row * 256;
    float acc = 0.f;
    #pragma unroll 8
    for (int k = 0; k < 256; ++k) acc += xr[k] * Ws[k * 8 + c];
    float* lp = &logits[(size_t)row * 8 + c];
    if (FIRST) *lp = acc + blin[c];
    else       *lp += acc;
}

__global__ void log_softmax_k(const float* __restrict__ logits, float* __restrict__ out) {
    int row = blockIdx.x * blockDim.x + threadIdx.x;
    if (row >= N_NODES) return;
    float4 a = *(const float4*)&logits[(size_t)row * 8];
    float4 b = *(const float4*)&logits[(size_t)row * 8 + 4];
    float m = fmaxf(fmaxf(fmaxf(a.x, a.y), fmaxf(a.z, a.w)),
                    fmaxf(fmaxf(b.x, b.y), fmaxf(b.z, b.w)));
    float s = expf(a.x - m) + expf(a.y - m) + expf(a.z - m) + expf(a.w - m)
            + expf(b.x - m) + expf(b.y - m) + expf(b.z - m) + expf(b.w - m);
    float ls = logf(s) + m;
    float* o = &out[(size_t)row * 8];
    o[0] = a.x - ls; o[1] = a.y - ls; o[2] = a.z - ls; o[3] = a.w - ls;
    o[4] = b.x - ls; o[5] = b.y - ls; o[6] = b.z - ls; o[7] = b.w - ls;
}

// ---------------- driver ----------------

extern "C" void kernel_launch(void* const* d_in, const int* in_sizes, int n_in,
                              void* d_out, int out_size, void* d_ws, size_t ws_size,
                              hipStream_t stream) {
    const float* x    = (const float*)d_in[0];
    const int*   ei   = (const int*)d_in[1];
    const float* ewp  = (const float*)d_in[2];
    const float* W1   = (const float*)d_in[3];
    const float* b1   = (const float*)d_in[4];
    const float* W2   = (const float*)d_in[5];
    const float* b2   = (const float*)d_in[6];
    const float* W3   = (const float*)d_in[7];
    const float* b3   = (const float*)d_in[8];
    const float* Wlin = (const float*)d_in[9];
    const float* blin = (const float*)d_in[10];
    float* out = (float*)d_out;

    const int* src = ei;
    const int* dst = ei + N_EDGES;

    float* ws = (float*)d_ws;
    float* norm    = ws;                                     // E
    float* norm3   = norm  + N_EDGES;                        // E
    float* dinv    = norm3 + N_EDGES;                        // N
    float* dinv3   = dinv  + N_NODES;                        // N
    float* logits  = dinv3 + N_NODES;                        // N*8
    float* e_w     = logits + (size_t)N_NODES * 8;           // E
    float* e_w3    = e_w + N_EDGES;                          // E
    int*   cnt     = (int*)(e_w3 + N_EDGES);                 // N
    int*   cur     = cnt + N_NODES;                          // N
    int*   row_start = cur + N_NODES;                        // N+1
    int*   e_src   = row_start + N_NODES + 1;                // E
    float* bufA    = (float*)(e_src + N_EDGES) + 64;         // N*256 (aligned)
    float* bufB    = bufA + (size_t)N_NODES * 256;
    float* bufC    = bufB + (size_t)N_NODES * 256;

    dim3 blk(256);
    int nodeBlocks  = (N_NODES + 255) / 256;
    int edgeBlocks  = (N_EDGES + 255) / 256;
    int gathBlocks  = (N_NODES + 3) / 4;
    int rowBlocks32 = (N_NODES + 31) / 32;

    // prep + CSR
    init_k<<<nodeBlocks, blk, 0, stream>>>(dinv, dinv3, cnt, cur);
    edge_deg_k<<<edgeBlocks, blk, 0, stream>>>(ewp, dst, dinv, dinv3, cnt, norm);
    finalize_dinv_k<<<nodeBlocks, blk, 0, stream>>>(dinv, dinv3);
    compute_norm_k<<<edgeBlocks, blk, 0, stream>>>(src, dst, dinv, dinv3, norm, norm3);
    scan_k<<<1, 1024, 0, stream>>>(cnt, row_start);
    fill_k<<<edgeBlocks, blk, 0, stream>>>(src, dst, norm, norm3, row_start, cur,
                                           e_src, e_w, e_w3);

    dim3 gemmGrid((N_NODES + 63) / 64, 4);

    // ---- layer 1: x -> x1 in bufB, h in bufA
    gemm_f32_k<<<gemmGrid, blk, 0, stream>>>(x, W1, bufA, N_NODES, NFEAT);
    gather_k<true><<<gathBlocks, blk, 0, stream>>>(bufA, row_start, e_src, e_w,
                                                   dinv, b1, bufB);
    logits_acc_k<true><<<rowBlocks32, blk, 0, stream>>>(bufB, Wlin, blin, logits, 0);

    // ---- layer 2: x1 -> x2 in bufC
    gemm_f32_k<<<gemmGrid, blk, 0, stream>>>(bufB, W2, bufA, N_NODES, NHID);
    gather_k<true><<<gathBlocks, blk, 0, stream>>>(bufA, row_start, e_src, e_w,
                                                   dinv, b2, bufC);
    logits_acc_k<false><<<rowBlocks32, blk, 0, stream>>>(bufC, Wlin, blin, logits, 1);

    // ---- layer 3: x2 -> x3 in bufB (ones edge weights)
    gemm_f32_k<<<gemmGrid, blk, 0, stream>>>(bufC, W3, bufA, N_NODES, NHID);
    gather_k<false><<<gathBlocks, blk, 0, stream>>>(bufA, row_start, e_src, e_w3,
                                                    dinv3, b3, bufB);
    logits_acc_k<false><<<rowBlocks32, blk, 0, stream>>>(bufB, Wlin, blin, logits, 2);

    // ---- output
    log_softmax_k<<<nodeBlocks, blk, 0, stream>>>(logits, out);
}

// Round 3
// 488.681 us; speedup vs baseline: 9.4975x; 1.8862x over previous
//
#include <hip/hip_runtime.h>
#include <math.h>

#define N_NODES 50000
#define N_EDGES 400000
#define M_PAD 50048
#define NFEAT 512
#define NHID 256
#define NCLASS 8

typedef unsigned short u16;
typedef __attribute__((ext_vector_type(8))) unsigned short u16x8;
typedef __attribute__((ext_vector_type(8))) short s16x8;
typedef __attribute__((ext_vector_type(4))) float f32x4;

__device__ __forceinline__ float bf2f(u16 u) {
    union { unsigned int i; float f; } v; v.i = ((unsigned int)u) << 16; return v.f;
}
__device__ __forceinline__ float bf2f_hi(unsigned int packed) {
    union { unsigned int i; float f; } v; v.i = packed & 0xffff0000u; return v.f;
}
__device__ __forceinline__ float bf2f_lo(unsigned int packed) {
    union { unsigned int i; float f; } v; v.i = packed << 16; return v.f;
}
__device__ __forceinline__ u16 f2bf(float f) {
    union { float f; unsigned int i; } v; v.f = f;
    unsigned int r = v.i + 0x7fffu + ((v.i >> 16) & 1u);
    return (u16)(r >> 16);
}

// ---------------- prep: degrees, norms, CSR ----------------

__global__ void init_k(float* deg, float* deg3, int* cnt, int* cur) {
    int i = blockIdx.x * blockDim.x + threadIdx.x;
    if (i < N_NODES) { deg[i] = 1.0f; deg3[i] = 1.0f; cnt[i] = 0; cur[i] = 0; }
}

__global__ void edge_deg_k(const float* __restrict__ p, const int* __restrict__ dst,
                           float* __restrict__ deg, float* __restrict__ deg3,
                           int* __restrict__ cnt, float* __restrict__ ew_out) {
    int e = blockIdx.x * blockDim.x + threadIdx.x;
    if (e >= N_EDGES) return;
    float ew = 1.0f / (1.0f + expf(-p[e]));
    ew_out[e] = ew;
    int d = dst[e];
    atomicAdd(&deg[d], ew);
    atomicAdd(&deg3[d], 1.0f);
    atomicAdd(&cnt[d], 1);
}

__global__ void finalize_dinv_k(float* deg, float* deg3) {
    int i = blockIdx.x * blockDim.x + threadIdx.x;
    if (i < N_NODES) {
        deg[i]  = 1.0f / sqrtf(deg[i]);
        deg3[i] = 1.0f / sqrtf(deg3[i]);
    }
}

__global__ void compute_norm_k(const int* __restrict__ src, const int* __restrict__ dst,
                               const float* __restrict__ dinv, const float* __restrict__ dinv3,
                               float* __restrict__ norm /* in: ew */, float* __restrict__ norm3) {
    int e = blockIdx.x * blockDim.x + threadIdx.x;
    if (e >= N_EDGES) return;
    int s = src[e], d = dst[e];
    float ew = norm[e];
    norm[e]  = dinv[s] * ew * dinv[d];
    norm3[e] = dinv3[s] * dinv3[d];
}

__global__ __launch_bounds__(1024) void scan_k(const int* __restrict__ cnt,
                                               int* __restrict__ row_start) {
    __shared__ int tmp[1024];
    const int CH = (N_NODES + 1023) / 1024;
    int t = threadIdx.x;
    int base = t * CH;
    int s = 0;
    for (int i = 0; i < CH; ++i) {
        int idx = base + i;
        if (idx < N_NODES) s += cnt[idx];
    }
    tmp[t] = s;
    __syncthreads();
    for (int off = 1; off < 1024; off <<= 1) {
        int v = 0;
        if (t >= off) v = tmp[t - off];
        __syncthreads();
        if (t >= off) tmp[t] += v;
        __syncthreads();
    }
    int run = (t == 0) ? 0 : tmp[t - 1];
    for (int i = 0; i < CH; ++i) {
        int idx = base + i;
        if (idx < N_NODES) { row_start[idx] = run; run += cnt[idx]; }
    }
    if (t == 1023) row_start[N_NODES] = tmp[1022];
}

__global__ void fill_k(const int* __restrict__ src, const int* __restrict__ dst,
                       const float* __restrict__ norm, const float* __restrict__ norm3,
                       const int* __restrict__ row_start, int* __restrict__ cur,
                       int* __restrict__ e_src, float* __restrict__ e_w,
                       float* __restrict__ e_w3) {
    int e = blockIdx.x * blockDim.x + threadIdx.x;
    if (e >= N_EDGES) return;
    int d = dst[e];
    int p = atomicAdd(&cur[d], 1);
    int slot = row_start[d] + p;
    e_src[slot] = src[e];
    e_w[slot]   = norm[e];
    e_w3[slot]  = norm3[e];
}

// ---------------- conversions ----------------

// x fp32 [50000][512] -> xb bf16 [M_PAD][512] (pad rows zero)
__global__ void convx_k(const float* __restrict__ x, u16* __restrict__ xb) {
    int idx = blockIdx.x * 256 + threadIdx.x;       // one 8-elem chunk
    if (idx >= M_PAD * (NFEAT / 8)) return;
    int row = idx >> 6;                              // 64 chunks per row
    size_t e0 = (size_t)idx * 8;
    u16x8 o = {0, 0, 0, 0, 0, 0, 0, 0};
    if (row < N_NODES) {
        float4 a = *(const float4*)&x[e0];
        float4 b = *(const float4*)&x[e0 + 4];
        o[0] = f2bf(a.x); o[1] = f2bf(a.y); o[2] = f2bf(a.z); o[3] = f2bf(a.w);
        o[4] = f2bf(b.x); o[5] = f2bf(b.y); o[6] = f2bf(b.z); o[7] = f2bf(b.w);
    }
    *(u16x8*)&xb[e0] = o;
}

// W fp32 [K][256] -> Wt bf16 [256][K]
__global__ void wtrans_k(const float* __restrict__ W, u16* __restrict__ Wt, int K) {
    int idx = blockIdx.x * 256 + threadIdx.x;
    if (idx >= 256 * K) return;
    int n = idx / K, k = idx - n * K;
    Wt[idx] = f2bf(W[(size_t)k * 256 + n]);
}

// zero pad rows [50000, M_PAD) of two bf16 activation buffers
__global__ void zeropad_k(u16* a, u16* b) {
    int i = blockIdx.x * 256 + threadIdx.x;
    if (i < (M_PAD - N_NODES) * 256) {
        a[(size_t)N_NODES * 256 + i] = 0;
        b[(size_t)N_NODES * 256 + i] = 0;
    }
}

// ---------------- bf16 MFMA GEMM: C[M_PAD x 256] = A[M_PAD x K] @ BT[256 x K]^T ----------------
// 128x128 tile, 4 waves (2x2), each wave 64x64 via 4x4 frags of 16x16x32.

__global__ __launch_bounds__(256) void gemm_bf16_k(const u16* __restrict__ A,
                                                   const u16* __restrict__ BT,
                                                   u16* __restrict__ C, int K) {
    __shared__ u16 Asl[128 * 40];   // row stride 40 elems (80 B): bank-phase spread
    __shared__ u16 Bsl[128 * 40];
    int tid = threadIdx.x;
    int lane = tid & 63;
    int wid = tid >> 6;
    int wm = wid >> 1, wn = wid & 1;
    int row0 = blockIdx.x * 128;
    int col0 = blockIdx.y * 128;

    // staging: 512 16B-chunks per operand tile, 2 per thread
    int c0 = tid, c1 = tid + 256;
    int ar0 = c0 >> 2, ak0 = (c0 & 3) << 3;
    int ar1 = c1 >> 2, ak1 = (c1 & 3) << 3;
    const u16* Ag0 = A + (size_t)(row0 + ar0) * K + ak0;
    const u16* Ag1 = A + (size_t)(row0 + ar1) * K + ak1;
    const u16* Bg0 = BT + (size_t)(col0 + ar0) * K + ak0;
    const u16* Bg1 = BT + (size_t)(col0 + ar1) * K + ak1;
    int la0 = ar0 * 40 + ak0, la1 = ar1 * 40 + ak1;

    u16x8 ra0 = *(const u16x8*)Ag0;
    u16x8 ra1 = *(const u16x8*)Ag1;
    u16x8 rb0 = *(const u16x8*)Bg0;
    u16x8 rb1 = *(const u16x8*)Bg1;

    f32x4 acc[4][4] = {};

    int arow = wm * 64 + (lane & 15);
    int bcol = wn * 64 + (lane & 15);
    int kg = (lane >> 4) << 3;

    int nt = K >> 5;
    for (int t = 0; t < nt; ++t) {
        __syncthreads();
        *(u16x8*)&Asl[la0] = ra0; *(u16x8*)&Asl[la1] = ra1;
        *(u16x8*)&Bsl[la0] = rb0; *(u16x8*)&Bsl[la1] = rb1;
        __syncthreads();
        if (t + 1 < nt) {                       // issue-early prefetch of next K-tile
            int ko = (t + 1) << 5;
            ra0 = *(const u16x8*)(Ag0 + ko);
            ra1 = *(const u16x8*)(Ag1 + ko);
            rb0 = *(const u16x8*)(Bg0 + ko);
            rb1 = *(const u16x8*)(Bg1 + ko);
        }
        s16x8 af[4], bf[4];
        #pragma unroll
        for (int m = 0; m < 4; ++m)
            af[m] = *(const s16x8*)&Asl[(arow + m * 16) * 40 + kg];
        #pragma unroll
        for (int n = 0; n < 4; ++n)
            bf[n] = *(const s16x8*)&Bsl[(bcol + n * 16) * 40 + kg];
        #pragma unroll
        for (int m = 0; m < 4; ++m)
            #pragma unroll
            for (int n = 0; n < 4; ++n)
                acc[m][n] = __builtin_amdgcn_mfma_f32_16x16x32_bf16(af[m], bf[n], acc[m][n], 0, 0, 0);
    }

    // C/D layout: col = lane&15, row = (lane>>4)*4 + r
    int crow0 = row0 + wm * 64 + ((lane >> 4) << 2);
    int ccol  = col0 + wn * 64 + (lane & 15);
    #pragma unroll
    for (int m = 0; m < 4; ++m)
        #pragma unroll
        for (int n = 0; n < 4; ++n)
            #pragma unroll
            for (int r = 0; r < 4; ++r)
                C[(size_t)(crow0 + m * 16 + r) * 256 + ccol + n * 16] = f2bf(acc[m][n][r]);
}

// ---------------- fused gather (bf16 in/out): out = sum h[src]*w + h[node]*dinv^2 + b, opt ReLU ----------------

template <bool RELU>
__global__ __launch_bounds__(256) void gather_k(const u16* __restrict__ h,
                                                const int* __restrict__ row_start,
                                                const int* __restrict__ e_src,
                                                const float* __restrict__ e_w,
                                                const float* __restrict__ dinv,
                                                const float* __restrict__ bias,
                                                u16* __restrict__ outb) {
    int node = blockIdx.x * 4 + (threadIdx.x >> 6);
    if (node >= N_NODES) return;
    int lane = threadIdx.x & 63;

    float di = dinv[node];
    float sw = di * di;
    uint2 hv = *(const uint2*)(h + (size_t)node * 256 + lane * 4);
    float4 acc;
    acc.x = bf2f_lo(hv.x) * sw; acc.y = bf2f_hi(hv.x) * sw;
    acc.z = bf2f_lo(hv.y) * sw; acc.w = bf2f_hi(hv.y) * sw;

    int beg = row_start[node], end = row_start[node + 1];
    for (int j = beg; j < end; ++j) {
        int sn  = e_src[j];
        float w = e_w[j];
        uint2 uv = *(const uint2*)(h + (size_t)sn * 256 + lane * 4);
        acc.x += bf2f_lo(uv.x) * w; acc.y += bf2f_hi(uv.x) * w;
        acc.z += bf2f_lo(uv.y) * w; acc.w += bf2f_hi(uv.y) * w;
    }
    float4 bv = ((const float4*)bias)[lane];
    acc.x += bv.x; acc.y += bv.y; acc.z += bv.z; acc.w += bv.w;
    if (RELU) {
        acc.x = fmaxf(acc.x, 0.f); acc.y = fmaxf(acc.y, 0.f);
        acc.z = fmaxf(acc.z, 0.f); acc.w = fmaxf(acc.w, 0.f);
    }
    uint2 o;
    o.x = (unsigned int)f2bf(acc.x) | ((unsigned int)f2bf(acc.y) << 16);
    o.y = (unsigned int)f2bf(acc.z) | ((unsigned int)f2bf(acc.w) << 16);
    *(uint2*)(outb + (size_t)node * 256 + lane * 4) = o;
}

// ---------------- final linear (bf16 x, accumulated per segment) + log_softmax ----------------

template <bool FIRST>
__global__ __launch_bounds__(256) void logits_acc_k(const u16* __restrict__ x,
                                                    const float* __restrict__ Wlin,
                                                    const float* __restrict__ blin,
                                                    float* __restrict__ logits, int seg) {
    __shared__ float Ws[256 * 8];
    int tid = threadIdx.x;
    const float* Wseg = Wlin + (size_t)seg * 256 * 8;
    for (int i = tid; i < 2048; i += 256) Ws[i] = Wseg[i];
    __syncthreads();
    int row = blockIdx.x * 32 + (tid >> 3);
    int c = tid & 7;
    if (row >= N_NODES) return;
    const u16* xr = x + (size_t)row * 256;
    float acc = 0.f;
    for (int k8 = 0; k8 < 32; ++k8) {
        u16x8 v = *(const u16x8*)&xr[k8 * 8];
        #pragma unroll
        for (int i = 0; i < 8; ++i) acc += bf2f(v[i]) * Ws[(k8 * 8 + i) * 8 + c];
    }
    float* lp = &logits[(size_t)row * 8 + c];
    if (FIRST) *lp = acc + blin[c];
    else       *lp += acc;
}

__global__ void log_softmax_k(const float* __restrict__ logits, float* __restrict__ out) {
    int row = blockIdx.x * blockDim.x + threadIdx.x;
    if (row >= N_NODES) return;
    float4 a = *(const float4*)&logits[(size_t)row * 8];
    float4 b = *(const float4*)&logits[(size_t)row * 8 + 4];
    float m = fmaxf(fmaxf(fmaxf(a.x, a.y), fmaxf(a.z, a.w)),
                    fmaxf(fmaxf(b.x, b.y), fmaxf(b.z, b.w)));
    float s = expf(a.x - m) + expf(a.y - m) + expf(a.z - m) + expf(a.w - m)
            + expf(b.x - m) + expf(b.y - m) + expf(b.z - m) + expf(b.w - m);
    float ls = logf(s) + m;
    float* o = &out[(size_t)row * 8];
    o[0] = a.x - ls; o[1] = a.y - ls; o[2] = a.z - ls; o[3] = a.w - ls;
    o[4] = b.x - ls; o[5] = b.y - ls; o[6] = b.z - ls; o[7] = b.w - ls;
}

// ---------------- driver ----------------

extern "C" void kernel_launch(void* const* d_in, const int* in_sizes, int n_in,
                              void* d_out, int out_size, void* d_ws, size_t ws_size,
                              hipStream_t stream) {
    const float* x    = (const float*)d_in[0];
    const int*   ei   = (const int*)d_in[1];
    const float* ewp  = (const float*)d_in[2];
    const float* W1   = (const float*)d_in[3];
    const float* b1   = (const float*)d_in[4];
    const float* W2   = (const float*)d_in[5];
    const float* b2   = (const float*)d_in[6];
    const float* W3   = (const float*)d_in[7];
    const float* b3   = (const float*)d_in[8];
    const float* Wlin = (const float*)d_in[9];
    const float* blin = (const float*)d_in[10];
    float* out = (float*)d_out;

    const int* src = ei;
    const int* dst = ei + N_EDGES;

    float* ws = (float*)d_ws;
    float* norm   = ws;                                  // E (ew -> norm in place)
    float* norm3  = norm + N_EDGES;                      // E
    float* e_w    = norm3 + N_EDGES;                     // E
    float* e_w3   = e_w + N_EDGES;                       // E
    float* dinv   = e_w3 + N_EDGES;                      // N
    float* dinv3  = dinv + N_NODES;                      // N
    float* logits = dinv3 + N_NODES;                     // N*8
    int* cnt       = (int*)(logits + (size_t)N_NODES * 8);
    int* cur       = cnt + N_NODES;
    int* row_start = cur + N_NODES;                      // N+1
    int* e_src     = row_start + N_NODES + 1;            // E
    u16* bstart = (u16*)(((uintptr_t)(e_src + N_EDGES) + 127) & ~(uintptr_t)127);
    u16* xb  = bstart;                                   // M_PAD*512
    u16* hb  = xb  + (size_t)M_PAD * 512;                // M_PAD*256
    u16* x1b = hb  + (size_t)M_PAD * 256;
    u16* x2b = x1b + (size_t)M_PAD * 256;
    u16* x3b = x2b + (size_t)M_PAD * 256;
    u16* wt1 = x3b + (size_t)M_PAD * 256;                // 256*512
    u16* wt2 = wt1 + 256 * 512;                          // 256*256
    u16* wt3 = wt2 + 256 * 256;

    dim3 blk(256);
    int nodeBlocks  = (N_NODES + 255) / 256;
    int edgeBlocks  = (N_EDGES + 255) / 256;
    int gathBlocks  = (N_NODES + 3) / 4;
    int rowBlocks32 = (N_NODES + 31) / 32;
    dim3 gemmGrid(M_PAD / 128, 2);

    // prep + CSR
    init_k<<<nodeBlocks, blk, 0, stream>>>(dinv, dinv3, cnt, cur);
    edge_deg_k<<<edgeBlocks, blk, 0, stream>>>(ewp, dst, dinv, dinv3, cnt, norm);
    finalize_dinv_k<<<nodeBlocks, blk, 0, stream>>>(dinv, dinv3);
    compute_norm_k<<<edgeBlocks, blk, 0, stream>>>(src, dst, dinv, dinv3, norm, norm3);
    scan_k<<<1, 1024, 0, stream>>>(cnt, row_start);
    fill_k<<<edgeBlocks, blk, 0, stream>>>(src, dst, norm, norm3, row_start, cur,
                                           e_src, e_w, e_w3);

    // conversions
    convx_k<<<M_PAD * (NFEAT / 8) / 256, blk, 0, stream>>>(x, xb);
    wtrans_k<<<NFEAT, blk, 0, stream>>>(W1, wt1, NFEAT);
    wtrans_k<<<NHID, blk, 0, stream>>>(W2, wt2, NHID);
    wtrans_k<<<NHID, blk, 0, stream>>>(W3, wt3, NHID);
    zeropad_k<<<48, blk, 0, stream>>>(x1b, x2b);

    // ---- layer 1
    gemm_bf16_k<<<gemmGrid, blk, 0, stream>>>(xb, wt1, hb, NFEAT);
    gather_k<true><<<gathBlocks, blk, 0, stream>>>(hb, row_start, e_src, e_w, dinv, b1, x1b);
    logits_acc_k<true><<<rowBlocks32, blk, 0, stream>>>(x1b, Wlin, blin, logits, 0);

    // ---- layer 2
    gemm_bf16_k<<<gemmGrid, blk, 0, stream>>>(x1b, wt2, hb, NHID);
    gather_k<true><<<gathBlocks, blk, 0, stream>>>(hb, row_start, e_src, e_w, dinv, b2, x2b);
    logits_acc_k<false><<<rowBlocks32, blk, 0, stream>>>(x2b, Wlin, blin, logits, 1);

    // ---- layer 3 (ones edge weights)
    gemm_bf16_k<<<gemmGrid, blk, 0, stream>>>(x2b, wt3, hb, NHID);
    gather_k<false><<<gathBlocks, blk, 0, stream>>>(hb, row_start, e_src, e_w3, dinv3, b3, x3b);
    logits_acc_k<false><<<rowBlocks32, blk, 0, stream>>>(x3b, Wlin, blin, logits, 2);

    // ---- output
    log_softmax_k<<<nodeBlocks, blk, 0, stream>>>(logits, out);
}

// Round 4
// 374.113 us; speedup vs baseline: 12.4060x; 1.3062x over previous
//
#include <hip/hip_runtime.h>
#include <math.h>

#define N_NODES 50000
#define N_EDGES 400000
#define M_PAD 50048
#define NFEAT 512
#define NHID 256
#define NCLASS 8
#define SCAN_BLOCKS ((N_NODES + 255) / 256)   // 196

typedef unsigned short u16;
typedef __attribute__((ext_vector_type(8))) unsigned short u16x8;
typedef __attribute__((ext_vector_type(8))) short s16x8;
typedef __attribute__((ext_vector_type(4))) float f32x4;

__device__ __forceinline__ float bf2f(u16 u) {
    union { unsigned int i; float f; } v; v.i = ((unsigned int)u) << 16; return v.f;
}
__device__ __forceinline__ float bf2f_hi(unsigned int packed) {
    union { unsigned int i; float f; } v; v.i = packed & 0xffff0000u; return v.f;
}
__device__ __forceinline__ float bf2f_lo(unsigned int packed) {
    union { unsigned int i; float f; } v; v.i = packed << 16; return v.f;
}
__device__ __forceinline__ u16 f2bf(float f) {
    union { float f; unsigned int i; } v; v.f = f;
    unsigned int r = v.i + 0x7fffu + ((v.i >> 16) & 1u);
    return (u16)(r >> 16);
}

// ---------------- prep: degrees, CSR ----------------

__global__ void init_k(float* deg, int* cnt, int* cur) {
    int i = blockIdx.x * blockDim.x + threadIdx.x;
    if (i < N_NODES) { deg[i] = 1.0f; cnt[i] = 0; cur[i] = 0; }
}

__global__ void edge_deg_k(const float* __restrict__ p, const int* __restrict__ dst,
                           float* __restrict__ deg, int* __restrict__ cnt,
                           float* __restrict__ ew_out) {
    int e = blockIdx.x * blockDim.x + threadIdx.x;
    if (e >= N_EDGES) return;
    float ew = 1.0f / (1.0f + expf(-p[e]));
    ew_out[e] = ew;
    int d = dst[e];
    atomicAdd(&deg[d], ew);
    atomicAdd(&cnt[d], 1);
}

// dinv = rsqrt(deg); dinv3 = rsqrt(1 + cnt)   (unweighted deg3 == cnt+1 exactly)
__global__ void finalize_dinv_k(float* __restrict__ deg, const int* __restrict__ cnt,
                                float* __restrict__ dinv3) {
    int i = blockIdx.x * blockDim.x + threadIdx.x;
    if (i < N_NODES) {
        deg[i]   = 1.0f / sqrtf(deg[i]);
        dinv3[i] = 1.0f / sqrtf(1.0f + (float)cnt[i]);
    }
}

// hierarchical exclusive scan: cnt[N] -> row_start[N+1]
__global__ __launch_bounds__(256) void scan1_k(const int* __restrict__ cnt,
                                               int* __restrict__ row_start,
                                               int* __restrict__ bsum) {
    __shared__ int tmp[256];
    int t = threadIdx.x;
    int g = blockIdx.x * 256 + t;
    int v = (g < N_NODES) ? cnt[g] : 0;
    tmp[t] = v;
    __syncthreads();
    #pragma unroll
    for (int off = 1; off < 256; off <<= 1) {
        int u = (t >= off) ? tmp[t - off] : 0;
        __syncthreads();
        tmp[t] += u;
        __syncthreads();
    }
    if (g < N_NODES) row_start[g] = tmp[t] - v;      // exclusive within block
    if (t == 255) bsum[blockIdx.x] = tmp[255];
}

__global__ __launch_bounds__(256) void scan2_k(int* __restrict__ bsum) {
    __shared__ int tmp[256];
    int t = threadIdx.x;
    int v = (t < SCAN_BLOCKS) ? bsum[t] : 0;
    tmp[t] = v;
    __syncthreads();
    #pragma unroll
    for (int off = 1; off < 256; off <<= 1) {
        int u = (t >= off) ? tmp[t - off] : 0;
        __syncthreads();
        tmp[t] += u;
        __syncthreads();
    }
    if (t < SCAN_BLOCKS) bsum[t] = tmp[t] - v;       // exclusive block offsets
}

__global__ __launch_bounds__(256) void scan3_k(int* __restrict__ row_start,
                                               const int* __restrict__ bsum) {
    int t = threadIdx.x;
    int g = blockIdx.x * 256 + t;
    if (g < N_NODES) row_start[g] += bsum[blockIdx.x];
    if (g == 0) row_start[N_NODES] = N_EDGES;
}

// fill CSR slots: packed (src, norm) and (src, norm3); norms computed in-flight
__global__ void fill_k(const int* __restrict__ src, const int* __restrict__ dst,
                       const float* __restrict__ ew, const float* __restrict__ dinv,
                       const float* __restrict__ dinv3,
                       const int* __restrict__ row_start, int* __restrict__ cur,
                       uint2* __restrict__ ep, uint2* __restrict__ ep3) {
    int e = blockIdx.x * blockDim.x + threadIdx.x;
    if (e >= N_EDGES) return;
    int s = src[e], d = dst[e];
    float w  = dinv[s] * ew[e] * dinv[d];
    float w3 = dinv3[s] * dinv3[d];
    int p = atomicAdd(&cur[d], 1);
    int slot = row_start[d] + p;
    ep[slot]  = make_uint2((unsigned int)s, __float_as_uint(w));
    ep3[slot] = make_uint2((unsigned int)s, __float_as_uint(w3));
}

// ---------------- conversions ----------------

__global__ void convx_k(const float* __restrict__ x, u16* __restrict__ xb) {
    int idx = blockIdx.x * 256 + threadIdx.x;
    if (idx >= M_PAD * (NFEAT / 8)) return;
    int row = idx >> 6;
    size_t e0 = (size_t)idx * 8;
    u16x8 o = {0, 0, 0, 0, 0, 0, 0, 0};
    if (row < N_NODES) {
        float4 a = *(const float4*)&x[e0];
        float4 b = *(const float4*)&x[e0 + 4];
        o[0] = f2bf(a.x); o[1] = f2bf(a.y); o[2] = f2bf(a.z); o[3] = f2bf(a.w);
        o[4] = f2bf(b.x); o[5] = f2bf(b.y); o[6] = f2bf(b.z); o[7] = f2bf(b.w);
    }
    *(u16x8*)&xb[e0] = o;
}

__global__ void wtrans_k(const float* __restrict__ W, u16* __restrict__ Wt, int K) {
    int idx = blockIdx.x * 256 + threadIdx.x;
    if (idx >= 256 * K) return;
    int n = idx / K, k = idx - n * K;
    Wt[idx] = f2bf(W[(size_t)k * 256 + n]);
}

__global__ void zeropad_k(u16* a, u16* b) {
    int i = blockIdx.x * 256 + threadIdx.x;
    if (i < (M_PAD - N_NODES) * 256) {
        a[(size_t)N_NODES * 256 + i] = 0;
        b[(size_t)N_NODES * 256 + i] = 0;
    }
}

// ---------------- bf16 MFMA GEMM: C[M_PAD x 256] = A[M_PAD x K] @ BT[256 x K]^T ----------------

__global__ __launch_bounds__(256) void gemm_bf16_k(const u16* __restrict__ A,
                                                   const u16* __restrict__ BT,
                                                   u16* __restrict__ C, int K) {
    __shared__ u16 Asl[128 * 40];
    __shared__ u16 Bsl[128 * 40];
    int tid = threadIdx.x;
    int lane = tid & 63;
    int wid = tid >> 6;
    int wm = wid >> 1, wn = wid & 1;
    int row0 = blockIdx.x * 128;
    int col0 = blockIdx.y * 128;

    int c0 = tid, c1 = tid + 256;
    int ar0 = c0 >> 2, ak0 = (c0 & 3) << 3;
    int ar1 = c1 >> 2, ak1 = (c1 & 3) << 3;
    const u16* Ag0 = A + (size_t)(row0 + ar0) * K + ak0;
    const u16* Ag1 = A + (size_t)(row0 + ar1) * K + ak1;
    const u16* Bg0 = BT + (size_t)(col0 + ar0) * K + ak0;
    const u16* Bg1 = BT + (size_t)(col0 + ar1) * K + ak1;
    int la0 = ar0 * 40 + ak0, la1 = ar1 * 40 + ak1;

    u16x8 ra0 = *(const u16x8*)Ag0;
    u16x8 ra1 = *(const u16x8*)Ag1;
    u16x8 rb0 = *(const u16x8*)Bg0;
    u16x8 rb1 = *(const u16x8*)Bg1;

    f32x4 acc[4][4] = {};

    int arow = wm * 64 + (lane & 15);
    int bcol = wn * 64 + (lane & 15);
    int kg = (lane >> 4) << 3;

    int nt = K >> 5;
    for (int t = 0; t < nt; ++t) {
        __syncthreads();
        *(u16x8*)&Asl[la0] = ra0; *(u16x8*)&Asl[la1] = ra1;
        *(u16x8*)&Bsl[la0] = rb0; *(u16x8*)&Bsl[la1] = rb1;
        __syncthreads();
        if (t + 1 < nt) {
            int ko = (t + 1) << 5;
            ra0 = *(const u16x8*)(Ag0 + ko);
            ra1 = *(const u16x8*)(Ag1 + ko);
            rb0 = *(const u16x8*)(Bg0 + ko);
            rb1 = *(const u16x8*)(Bg1 + ko);
        }
        s16x8 af[4], bf[4];
        #pragma unroll
        for (int m = 0; m < 4; ++m)
            af[m] = *(const s16x8*)&Asl[(arow + m * 16) * 40 + kg];
        #pragma unroll
        for (int n = 0; n < 4; ++n)
            bf[n] = *(const s16x8*)&Bsl[(bcol + n * 16) * 40 + kg];
        #pragma unroll
        for (int m = 0; m < 4; ++m)
            #pragma unroll
            for (int n = 0; n < 4; ++n)
                acc[m][n] = __builtin_amdgcn_mfma_f32_16x16x32_bf16(af[m], bf[n], acc[m][n], 0, 0, 0);
    }

    int crow0 = row0 + wm * 64 + ((lane >> 4) << 2);
    int ccol  = col0 + wn * 64 + (lane & 15);
    #pragma unroll
    for (int m = 0; m < 4; ++m)
        #pragma unroll
        for (int n = 0; n < 4; ++n)
            #pragma unroll
            for (int r = 0; r < 4; ++r)
                C[(size_t)(crow0 + m * 16 + r) * 256 + ccol + n * 16] = f2bf(acc[m][n][r]);
}

// ---------------- fused gather (bf16 in/out) ----------------

template <bool RELU>
__global__ __launch_bounds__(256) void gather_k(const u16* __restrict__ h,
                                                const int* __restrict__ row_start,
                                                const uint2* __restrict__ ep,
                                                const float* __restrict__ dinv,
                                                const float* __restrict__ bias,
                                                u16* __restrict__ outb) {
    int node = blockIdx.x * 4 + (threadIdx.x >> 6);
    if (node >= N_NODES) return;
    int lane = threadIdx.x & 63;

    float di = dinv[node];
    float sw = di * di;
    uint2 hv = *(const uint2*)(h + (size_t)node * 256 + lane * 4);
    float4 acc;
    acc.x = bf2f_lo(hv.x) * sw; acc.y = bf2f_hi(hv.x) * sw;
    acc.z = bf2f_lo(hv.y) * sw; acc.w = bf2f_hi(hv.y) * sw;

    int beg = row_start[node], end = row_start[node + 1];
    for (int j = beg; j < end; ++j) {
        uint2 e = ep[j];
        float w = __uint_as_float(e.y);
        uint2 uv = *(const uint2*)(h + (size_t)e.x * 256 + lane * 4);
        acc.x += bf2f_lo(uv.x) * w; acc.y += bf2f_hi(uv.x) * w;
        acc.z += bf2f_lo(uv.y) * w; acc.w += bf2f_hi(uv.y) * w;
    }
    float4 bv = ((const float4*)bias)[lane];
    acc.x += bv.x; acc.y += bv.y; acc.z += bv.z; acc.w += bv.w;
    if (RELU) {
        acc.x = fmaxf(acc.x, 0.f); acc.y = fmaxf(acc.y, 0.f);
        acc.z = fmaxf(acc.z, 0.f); acc.w = fmaxf(acc.w, 0.f);
    }
    uint2 o;
    o.x = (unsigned int)f2bf(acc.x) | ((unsigned int)f2bf(acc.y) << 16);
    o.y = (unsigned int)f2bf(acc.z) | ((unsigned int)f2bf(acc.w) << 16);
    *(uint2*)(outb + (size_t)node * 256 + lane * 4) = o;
}

// ---------------- final linear + log_softmax ----------------

template <bool FIRST>
__global__ __launch_bounds__(256) void logits_acc_k(const u16* __restrict__ x,
                                                    const float* __restrict__ Wlin,
                                                    const float* __restrict__ blin,
                                                    float* __restrict__ logits, int seg) {
    __shared__ float Ws[256 * 8];
    int tid = threadIdx.x;
    const float* Wseg = Wlin + (size_t)seg * 256 * 8;
    for (int i = tid; i < 2048; i += 256) Ws[i] = Wseg[i];
    __syncthreads();
    int row = blockIdx.x * 32 + (tid >> 3);
    int c = tid & 7;
    if (row >= N_NODES) return;
    const u16* xr = x + (size_t)row * 256;
    float acc = 0.f;
    for (int k8 = 0; k8 < 32; ++k8) {
        u16x8 v = *(const u16x8*)&xr[k8 * 8];
        #pragma unroll
        for (int i = 0; i < 8; ++i) acc += bf2f(v[i]) * Ws[(k8 * 8 + i) * 8 + c];
    }
    float* lp = &logits[(size_t)row * 8 + c];
    if (FIRST) *lp = acc + blin[c];
    else       *lp += acc;
}

__global__ void log_softmax_k(const float* __restrict__ logits, float* __restrict__ out) {
    int row = blockIdx.x * blockDim.x + threadIdx.x;
    if (row >= N_NODES) return;
    float4 a = *(const float4*)&logits[(size_t)row * 8];
    float4 b = *(const float4*)&logits[(size_t)row * 8 + 4];
    float m = fmaxf(fmaxf(fmaxf(a.x, a.y), fmaxf(a.z, a.w)),
                    fmaxf(fmaxf(b.x, b.y), fmaxf(b.z, b.w)));
    float s = expf(a.x - m) + expf(a.y - m) + expf(a.z - m) + expf(a.w - m)
            + expf(b.x - m) + expf(b.y - m) + expf(b.z - m) + expf(b.w - m);
    float ls = logf(s) + m;
    float* o = &out[(size_t)row * 8];
    o[0] = a.x - ls; o[1] = a.y - ls; o[2] = a.z - ls; o[3] = a.w - ls;
    o[4] = b.x - ls; o[5] = b.y - ls; o[6] = b.z - ls; o[7] = b.w - ls;
}

// ---------------- driver ----------------

extern "C" void kernel_launch(void* const* d_in, const int* in_sizes, int n_in,
                              void* d_out, int out_size, void* d_ws, size_t ws_size,
                              hipStream_t stream) {
    const float* x    = (const float*)d_in[0];
    const int*   ei   = (const int*)d_in[1];
    const float* ewp  = (const float*)d_in[2];
    const float* W1   = (const float*)d_in[3];
    const float* b1   = (const float*)d_in[4];
    const float* W2   = (const float*)d_in[5];
    const float* b2   = (const float*)d_in[6];
    const float* W3   = (const float*)d_in[7];
    const float* b3   = (const float*)d_in[8];
    const float* Wlin = (const float*)d_in[9];
    const float* blin = (const float*)d_in[10];
    float* out = (float*)d_out;

    const int* src = ei;
    const int* dst = ei + N_EDGES;

    float* ws = (float*)d_ws;
    float* ew     = ws;                                  // E (sigmoid weights)
    float* dinv   = ew + N_EDGES;                        // N (deg -> dinv in place)
    float* dinv3  = dinv + N_NODES;                      // N
    float* logits = dinv3 + N_NODES;                     // N*8
    int* cnt       = (int*)(logits + (size_t)N_NODES * 8);
    int* cur       = cnt + N_NODES;
    int* row_start = cur + N_NODES;                      // N+1
    int* bsum      = row_start + N_NODES + 1;            // SCAN_BLOCKS
    uint2* ep  = (uint2*)(((uintptr_t)(bsum + SCAN_BLOCKS) + 127) & ~(uintptr_t)127);  // E
    uint2* ep3 = ep + N_EDGES;                           // E
    u16* xb  = (u16*)(ep3 + N_EDGES);                    // M_PAD*512
    u16* hb  = xb  + (size_t)M_PAD * 512;                // M_PAD*256
    u16* x1b = hb  + (size_t)M_PAD * 256;
    u16* x2b = x1b + (size_t)M_PAD * 256;
    u16* x3b = x2b + (size_t)M_PAD * 256;
    u16* wt1 = x3b + (size_t)M_PAD * 256;                // 256*512
    u16* wt2 = wt1 + 256 * 512;
    u16* wt3 = wt2 + 256 * 256;

    dim3 blk(256);
    int nodeBlocks  = (N_NODES + 255) / 256;
    int edgeBlocks  = (N_EDGES + 255) / 256;
    int gathBlocks  = (N_NODES + 3) / 4;
    int rowBlocks32 = (N_NODES + 31) / 32;
    dim3 gemmGrid(M_PAD / 128, 2);

    // prep + CSR
    init_k<<<nodeBlocks, blk, 0, stream>>>(dinv, cnt, cur);
    edge_deg_k<<<edgeBlocks, blk, 0, stream>>>(ewp, dst, dinv, cnt, ew);
    finalize_dinv_k<<<nodeBlocks, blk, 0, stream>>>(dinv, cnt, dinv3);
    scan1_k<<<SCAN_BLOCKS, blk, 0, stream>>>(cnt, row_start, bsum);
    scan2_k<<<1, blk, 0, stream>>>(bsum);
    scan3_k<<<SCAN_BLOCKS, blk, 0, stream>>>(row_start, bsum);
    fill_k<<<edgeBlocks, blk, 0, stream>>>(src, dst, ew, dinv, dinv3, row_start, cur, ep, ep3);

    // conversions
    convx_k<<<M_PAD * (NFEAT / 8) / 256, blk, 0, stream>>>(x, xb);
    wtrans_k<<<NFEAT, blk, 0, stream>>>(W1, wt1, NFEAT);
    wtrans_k<<<NHID, blk, 0, stream>>>(W2, wt2, NHID);
    wtrans_k<<<NHID, blk, 0, stream>>>(W3, wt3, NHID);
    zeropad_k<<<48, blk, 0, stream>>>(x1b, x2b);

    // ---- layer 1
    gemm_bf16_k<<<gemmGrid, blk, 0, stream>>>(xb, wt1, hb, NFEAT);
    gather_k<true><<<gathBlocks, blk, 0, stream>>>(hb, row_start, ep, dinv, b1, x1b);
    logits_acc_k<true><<<rowBlocks32, blk, 0, stream>>>(x1b, Wlin, blin, logits, 0);

    // ---- layer 2
    gemm_bf16_k<<<gemmGrid, blk, 0, stream>>>(x1b, wt2, hb, NHID);
    gather_k<true><<<gathBlocks, blk, 0, stream>>>(hb, row_start, ep, dinv, b2, x2b);
    logits_acc_k<false><<<rowBlocks32, blk, 0, stream>>>(x2b, Wlin, blin, logits, 1);

    // ---- layer 3 (ones edge weights)
    gemm_bf16_k<<<gemmGrid, blk, 0, stream>>>(x2b, wt3, hb, NHID);
    gather_k<false><<<gathBlocks, blk, 0, stream>>>(hb, row_start, ep3, dinv3, b3, x3b);
    logits_acc_k<false><<<rowBlocks32, blk, 0, stream>>>(x3b, Wlin, blin, logits, 2);

    // ---- output
    log_softmax_k<<<nodeBlocks, blk, 0, stream>>>(logits, out);
}